// Round 2
// baseline (86.560 us; speedup 1.0000x reference)
//
#include <hip/hip_runtime.h>

// AllPoleDigitalFilter via overlap-and-discard.
// R15: TLP + shorter warm.
//  - Evidence: absmax bit-identical (0.03515625) across warm 320 -> 240+Kx
//    init => binding error is the warm-independent midpoint-tap approx;
//    warm error has headroom. Kernel ~37us = 320 serial samples at ~265
//    cyc/sample for ~22 instr/sample => latency-exposed at the forced
//    1 wave/SIMD (waves_per_eu(1,1), 800 waves / 1024 SIMDs).
//  - Change 1: LCH 40->16 (CHUNKS=4000, 2000 waves ~ 2/SIMD) and
//    waves_per_eu(2,4) to lift the occupancy cap -> TLP hides VALU latency
//    and I-fetch stalls.
//  - Change 2: warm 160 (3 frames/thread, serial ~212 avg) with a
//    first-order refined warm-start: y0 = K*x - sum a_m*(K*x hist)
//    (init error 0.38x -> 0.14x of zero-init).
// Structure (validated R13/R14): per-8-group midpoint taps, exact
// per-sample gain, dual-aligned v2f history rings: wA[i]={y[2i],y[2i+1]}
// serves even samples, wB[i]={y[2i+1],y[2i+2]} serves odd samples ->
// v_pk_fma_f32 operands never need pair-building movs (1 mirror mov/sample).
// Packed negated coeffs {-a_{4+2r}, -a_{3+2r}} are parity-invariant.
// Taps 1,2 scalar (1-FMA inter-sample critical path). constexpr index
// helpers with +80 bias before %40, element-wise vector init, explicit
// component stores, all ring indices compile-time.

typedef float v2f __attribute__((ext_vector_type(2)));

#define BATCH 32
#define N_FRAMES 800
#define D_COEF 25
#define P_FRAME 80
#define T_SAMP 64000
#define LCH 16
#define CHUNKS 4000              // per batch row

// ring slot helpers (all args non-negative; +80 bias removes any doubt)
__device__ __forceinline__ constexpr int slotA(int s)  { return ((s + 80) % 40) / 2; }       // even s: wA[slotA].x=y[s]; odd s uses slotAy
__device__ __forceinline__ constexpr int slotAy(int s) { return ((s + 80 - 1) % 40) / 2; }   // odd s: wA[slotAy].y=y[s]
__device__ __forceinline__ constexpr int slotBx(int s) { return ((s + 80 - 1) % 40) / 2; }   // odd s: wB[slotBx].x=y[s]
__device__ __forceinline__ constexpr int slotBy(int s) { return ((s + 80 - 2) % 40) / 2; }   // even s: wB[slotBy].y=y[s]

__global__
__attribute__((amdgpu_flat_work_group_size(64, 64)))
__attribute__((amdgpu_waves_per_eu(2, 4)))
void lpc_kernel(const float* __restrict__ x,
                const float* __restrict__ a,
                float* __restrict__ out) {
    const int g = blockIdx.x * 64 + threadIdx.x;
    const int b = g / CHUNKS;
    const int ci = g - b * CHUNKS;
    const int s0 = ci * LCH;
    const int nb = (ci >= 10) ? (ci - 10) / 5 : 0;   // warm in [160, 224]
    const int t0 = nb * P_FRAME;

    const float* xrow = x + (size_t)b * T_SAMP;
    float* orow = out + (size_t)b * T_SAMP;
    const float* arow = a + (size_t)b * (N_FRAMES * D_COEF);

    v2f wA[20], wB[20];
#pragma unroll
    for (int i = 0; i < 20; ++i) {
        wA[i].x = 0.0f; wA[i].y = 0.0f;
        wB[i].x = 0.0f; wB[i].y = 0.0f;
    }

    const float inv_p = 1.0f / (float)P_FRAME;

    // First-order refined warm-start: ring positions P=0..23 hold
    // y[t0-24 .. t0-1]. Samples t0-48+i sit at p=32+i of frame nb-1.
    // z[i] = K(t)*x(t); y0[i] = z[24+i] - sum_m am[m]*z[24+i-m]
    // (taps interpolated at the history midpoint p~56 -> frac 0.7).
    if (nb > 0) {
        const float* rm1 = arow + (nb - 1) * D_COEF;
        const float* r00 = arow + nb * D_COEF;
        const float gm1 = rm1[0];
        const float dg = (r00[0] - gm1) * inv_p;

        float z[48];
#pragma unroll
        for (int q = 0; q < 12; ++q) {
            float4 xq = *(const float4*)(xrow + t0 - 48 + 4 * q);
            z[4 * q + 0] = xq.x; z[4 * q + 1] = xq.y;
            z[4 * q + 2] = xq.z; z[4 * q + 3] = xq.w;
        }
#pragma unroll
        for (int i = 0; i < 48; ++i) {
            float Kv = fmaf(dg, (float)(32 + i), gm1);
            z[i] *= Kv;
        }
        float am[24];
#pragma unroll
        for (int m = 0; m < 24; ++m) {
            float c0 = rm1[1 + m];
            am[m] = fmaf(r00[1 + m] - c0, 0.7f, c0);
        }
#pragma unroll
        for (int i = 0; i < 24; ++i) {
            float s = z[24 + i];
#pragma unroll
            for (int m = 1; m <= 24; ++m) s = fmaf(-am[m - 1], z[24 + i - m], s);
            if (i & 1) { wA[slotAy(i)].y = s; wB[slotBx(i)].x = s; }
            else       { wA[slotA(i)].x  = s; wB[slotBy(i)].y = s; }
        }
    }

    float4 xc0 = *(const float4*)(xrow + t0);
    float4 xc1 = *(const float4*)(xrow + t0 + 4);
    float4 xn0 = *(const float4*)(xrow + t0 + 8);
    float4 xn1 = *(const float4*)(xrow + t0 + 12);

#pragma unroll 1
    for (int f = 0; f < 3; ++f) {                 // 3 frames: warm<=224 + 16 out
        const int n = nb + f;
        const int n1 = (n + 1 < N_FRAMES) ? n + 1 : N_FRAMES - 1;
        const float* r0 = arow + n * D_COEF;
        const float* r1 = arow + n1 * D_COEF;

        float g0 = r0[0];
        float dk = (r1[0] - g0) * inv_p;
        float k = g0;

        float nc1, nc2, dn1, dn2;
        {
            float c1 = r0[1], c2 = r0[2];
            float d1 = (r1[1] - c1) * inv_p;
            float d2 = (r1[2] - c2) * inv_p;
            nc1 = -fmaf(d1, 3.5f, c1);  dn1 = -8.0f * d1;
            nc2 = -fmaf(d2, 3.5f, c2);  dn2 = -8.0f * d2;
        }
        v2f cp[11], d8[11];
#pragma unroll
        for (int r = 0; r < 11; ++r) {
            float cLo = r0[4 + 2 * r], cHi = r0[3 + 2 * r];
            float dLo = (r1[4 + 2 * r] - cLo) * inv_p;
            float dHi = (r1[3 + 2 * r] - cHi) * inv_p;
            cp[r].x = -fmaf(dLo, 3.5f, cLo);
            cp[r].y = -fmaf(dHi, 3.5f, cHi);
            d8[r].x = -8.0f * dLo;
            d8[r].y = -8.0f * dHi;
        }

        const int tf = t0 + f * P_FRAME;

#pragma unroll
        for (int gg = 0; gg < 10; ++gg) {
            const int tg = tf + gg * 8;
            int tp = tg + 16; if (tp > T_SAMP - 8) tp = T_SAMP - 8;
            float4 xf0 = *(const float4*)(xrow + tp);
            float4 xf1 = *(const float4*)(xrow + tp + 4);

#pragma unroll
            for (int j = 0; j < 8; ++j) {
                const int P = 24 + gg * 8 + j;        // compile-time ring pos
                float xv = (j == 0) ? xc0.x : (j == 1) ? xc0.y
                         : (j == 2) ? xc0.z : (j == 3) ? xc0.w
                         : (j == 4) ? xc1.x : (j == 5) ? xc1.y
                         : (j == 6) ? xc1.z : xc1.w;
                float e = k * xv;

                // taps 3..24: 11 pk ops, 3 chains; pair r covers lags 3+2r,4+2r
                v2f A, B, C;
#pragma unroll
                for (int r = 0; r < 11; ++r) {
                    // pair {y[P-4-2r], y[P-3-2r]}: even P from wA, odd P from wB
                    v2f pr = (P & 1) ? wB[slotBx(P - 3 - 2 * r)]
                                     : wA[slotA(P - 4 - 2 * r)];
                    if (r == 0)          A = cp[r] * pr;
                    else if (r == 1)     B = cp[r] * pr;
                    else if (r == 2)     C = cp[r] * pr;
                    else if (r % 3 == 0) A += cp[r] * pr;
                    else if (r % 3 == 1) B += cp[r] * pr;
                    else                 C += cp[r] * pr;
                }
                v2f S = (A + B) + C;
                float t1 = e + (S.x + S.y);
                float ym1 = (P & 1) ? wA[slotA(P - 1)].x  : wA[slotAy(P - 1)].y;  // y[P-1]
                float ym2 = (P & 1) ? wA[slotAy(P - 2)].y : wA[slotA(P - 2)].x;   // y[P-2]
                float u = fmaf(nc2, ym2, t1);
                float y = fmaf(nc1, ym1, u);

                // mirror write into both rings
                if (P & 1) {
                    wA[slotAy(P)].y = y;
                    wB[slotBx(P)].x = y;
                } else {
                    wA[slotA(P)].x = y;
                    wB[slotBy(P)].y = y;
                }
                k += dk;
            }

            if ((unsigned)(tg - s0) < 16u) {          // tg, s0 multiples of 8
                const int Q = 24 + gg * 8;            // Q even -> pairs from wA
                *(float4*)(orow + tg)     = make_float4(wA[slotA(Q + 0)].x, wA[slotA(Q + 0)].y,
                                                        wA[slotA(Q + 2)].x, wA[slotA(Q + 2)].y);
                *(float4*)(orow + tg + 4) = make_float4(wA[slotA(Q + 4)].x, wA[slotA(Q + 4)].y,
                                                        wA[slotA(Q + 6)].x, wA[slotA(Q + 6)].y);
            }
            if (gg < 9) {
                nc1 += dn1; nc2 += dn2;
#pragma unroll
                for (int r = 0; r < 11; ++r) cp[r] += d8[r];   // v_pk_add_f32
            }
            xc0 = xn0; xc1 = xn1;                     // rotate at group END
            xn0 = xf0; xn1 = xf1;
        }
    }
}

extern "C" void kernel_launch(void* const* d_in, const int* in_sizes, int n_in,
                              void* d_out, int out_size, void* d_ws, size_t ws_size,
                              hipStream_t stream) {
    const float* x = (const float*)d_in[0];
    const float* a = (const float*)d_in[1];
    float* out = (float*)d_out;

    dim3 block(64);
    dim3 grid(BATCH * CHUNKS / 64);      // 2000 one-wave blocks (~2 waves/SIMD)
    hipLaunchKernelGGL(lpc_kernel, grid, block, 0, stream, x, a, out);
}

// Round 3
// 75.723 us; speedup vs baseline: 1.1431x; 1.1431x over previous
//
#include <hip/hip_runtime.h>

// AllPoleDigitalFilter via overlap-and-discard.
// R16: revert R15's TLP regression (aggregate work x2.08 ate the hiding
// gain); keep its validated accuracy result (warm 160 + first-order
// warm-start => absmax bit-identical 0.03515625).
//  - Config: LCH=40, CHUNKS=1600, 800 waves, waves_per_eu(1,1) (512-VGPR
//    budget, known-good R14 regime).
//  - Lever 1 (validated): nb=(ci-4)>>1 -> warm 160/200, 3 frames
//    (240 serial samples, was 320) + first-order K*x warm-start
//    y0 = K*x - sum a_m*(K*x hist) over 48-sample z window.
//  - Lever 2 (numerics-identical): register double-buffer of coefficient
//    rows ccur/cnxt/cfut. Frame-start cp/d8 setup reads resident regs;
//    frame n+2's 25-float row prefetched at frame-n start (hidden under
//    ~9k cyc of compute). Removes the ~50 immediately-consumed gather
//    loads per frame (each ~32 cache lines at 0.78 waves/SIMD exposure)
//    and halves coefficient fetch traffic.
// Structure (validated R13/R14): per-8-group midpoint taps, exact
// per-sample gain, dual-aligned v2f history rings: wA[i]={y[2i],y[2i+1]}
// serves even samples, wB[i]={y[2i+1],y[2i+2]} serves odd samples ->
// v_pk_fma_f32 operands never need pair-building movs (1 mirror
// mov/sample). Packed negated coeffs {-a_{4+2r}, -a_{3+2r}} are
// parity-invariant. Taps 1,2 scalar (1-FMA inter-sample critical path).
// constexpr index helpers with +80 bias before %40, element-wise vector
// init, explicit component stores, all ring indices compile-time.

typedef float v2f __attribute__((ext_vector_type(2)));

#define BATCH 32
#define N_FRAMES 800
#define D_COEF 25
#define P_FRAME 80
#define T_SAMP 64000
#define LCH 40
#define CHUNKS 1600              // per batch row

// ring slot helpers (all args non-negative; +80 bias removes any doubt)
__device__ __forceinline__ constexpr int slotA(int s)  { return ((s + 80) % 40) / 2; }       // even s: wA[slotA].x=y[s]; odd s uses slotAy
__device__ __forceinline__ constexpr int slotAy(int s) { return ((s + 80 - 1) % 40) / 2; }   // odd s: wA[slotAy].y=y[s]
__device__ __forceinline__ constexpr int slotBx(int s) { return ((s + 80 - 1) % 40) / 2; }   // odd s: wB[slotBx].x=y[s]
__device__ __forceinline__ constexpr int slotBy(int s) { return ((s + 80 - 2) % 40) / 2; }   // even s: wB[slotBy].y=y[s]

__global__
__attribute__((amdgpu_flat_work_group_size(64, 64)))
__attribute__((amdgpu_waves_per_eu(1, 1)))
void lpc_kernel(const float* __restrict__ x,
                const float* __restrict__ a,
                float* __restrict__ out) {
    const int g = blockIdx.x * 64 + threadIdx.x;
    const int b = g / CHUNKS;
    const int ci = g - b * CHUNKS;
    const int s0 = ci * LCH;
    const int nb = (ci >= 4) ? ((ci - 4) >> 1) : 0;   // warm 160 (even ci) / 200 (odd ci); ci<4 exact from t=0
    const int t0 = nb * P_FRAME;

    const float* xrow = x + (size_t)b * T_SAMP;
    float* orow = out + (size_t)b * T_SAMP;
    const float* arow = a + (size_t)b * (N_FRAMES * D_COEF);

    v2f wA[20], wB[20];
#pragma unroll
    for (int i = 0; i < 20; ++i) {
        wA[i].x = 0.0f; wA[i].y = 0.0f;
        wB[i].x = 0.0f; wB[i].y = 0.0f;
    }

    const float inv_p = 1.0f / (float)P_FRAME;

    // Coefficient register double-buffer: ccur = frame nb, cnxt = frame nb+1.
    float ccur[D_COEF], cnxt[D_COEF], cfut[D_COEF];
    {
        const float* rc = arow + nb * D_COEF;
        const int n1i = (nb + 1 < N_FRAMES) ? nb + 1 : N_FRAMES - 1;
        const float* rn = arow + n1i * D_COEF;
#pragma unroll
        for (int q = 0; q < D_COEF; ++q) { ccur[q] = rc[q]; cnxt[q] = rn[q]; }
    }

    // First-order refined warm-start (validated R15): ring positions
    // P=0..23 hold y[t0-24 .. t0-1]. Samples t0-48+i sit at p=32+i of
    // frame nb-1. z[i] = K(t)*x(t); y0[i] = z[24+i] - sum_m am[m]*z[24+i-m]
    // (taps interpolated at the history midpoint p~56 -> frac 0.7).
    if (nb > 0) {
        const float* rm1 = arow + (nb - 1) * D_COEF;
        const float gm1 = rm1[0];
        const float dg = (ccur[0] - gm1) * inv_p;

        float z[48];
#pragma unroll
        for (int q = 0; q < 12; ++q) {
            float4 xq = *(const float4*)(xrow + t0 - 48 + 4 * q);
            z[4 * q + 0] = xq.x; z[4 * q + 1] = xq.y;
            z[4 * q + 2] = xq.z; z[4 * q + 3] = xq.w;
        }
#pragma unroll
        for (int i = 0; i < 48; ++i) {
            float Kv = fmaf(dg, (float)(32 + i), gm1);
            z[i] *= Kv;
        }
        float am[24];
#pragma unroll
        for (int m = 0; m < 24; ++m) {
            float c0 = rm1[1 + m];
            am[m] = fmaf(ccur[1 + m] - c0, 0.7f, c0);
        }
#pragma unroll
        for (int i = 0; i < 24; ++i) {
            float s = z[24 + i];
#pragma unroll
            for (int m = 1; m <= 24; ++m) s = fmaf(-am[m - 1], z[24 + i - m], s);
            if (i & 1) { wA[slotAy(i)].y = s; wB[slotBx(i)].x = s; }
            else       { wA[slotA(i)].x  = s; wB[slotBy(i)].y = s; }
        }
    }

    float4 xc0 = *(const float4*)(xrow + t0);
    float4 xc1 = *(const float4*)(xrow + t0 + 4);
    float4 xn0 = *(const float4*)(xrow + t0 + 8);
    float4 xn1 = *(const float4*)(xrow + t0 + 12);

#pragma unroll 1
    for (int f = 0; f < 3; ++f) {                 // 3 frames: warm<=200 + 40 out
        float g0 = ccur[0];
        float dk = (cnxt[0] - g0) * inv_p;
        float k = g0;

        float nc1, nc2, dn1, dn2;
        {
            float c1 = ccur[1], c2 = ccur[2];
            float d1 = (cnxt[1] - c1) * inv_p;
            float d2 = (cnxt[2] - c2) * inv_p;
            nc1 = -fmaf(d1, 3.5f, c1);  dn1 = -8.0f * d1;
            nc2 = -fmaf(d2, 3.5f, c2);  dn2 = -8.0f * d2;
        }
        v2f cp[11], d8[11];
#pragma unroll
        for (int r = 0; r < 11; ++r) {
            float cLo = ccur[4 + 2 * r], cHi = ccur[3 + 2 * r];
            float dLo = (cnxt[4 + 2 * r] - cLo) * inv_p;
            float dHi = (cnxt[3 + 2 * r] - cHi) * inv_p;
            cp[r].x = -fmaf(dLo, 3.5f, cLo);
            cp[r].y = -fmaf(dHi, 3.5f, cHi);
            d8[r].x = -8.0f * dLo;
            d8[r].y = -8.0f * dHi;
        }

        // Prefetch frame n+2's coefficient row; consumed at the rotation
        // after this frame's 80 samples (~9k cyc of hiding).
        if (f < 2) {
            const int n2 = (nb + f + 2 < N_FRAMES) ? nb + f + 2 : N_FRAMES - 1;
            const float* r2 = arow + n2 * D_COEF;
#pragma unroll
            for (int q = 0; q < D_COEF; ++q) cfut[q] = r2[q];
        }

        const int tf = t0 + f * P_FRAME;

#pragma unroll
        for (int gg = 0; gg < 10; ++gg) {
            const int tg = tf + gg * 8;
            int tp = tg + 16; if (tp > T_SAMP - 8) tp = T_SAMP - 8;
            float4 xf0 = *(const float4*)(xrow + tp);
            float4 xf1 = *(const float4*)(xrow + tp + 4);

#pragma unroll
            for (int j = 0; j < 8; ++j) {
                const int P = 24 + gg * 8 + j;        // compile-time ring pos
                float xv = (j == 0) ? xc0.x : (j == 1) ? xc0.y
                         : (j == 2) ? xc0.z : (j == 3) ? xc0.w
                         : (j == 4) ? xc1.x : (j == 5) ? xc1.y
                         : (j == 6) ? xc1.z : xc1.w;
                float e = k * xv;

                // taps 3..24: 11 pk ops, 3 chains; pair r covers lags 3+2r,4+2r
                v2f A, B, C;
#pragma unroll
                for (int r = 0; r < 11; ++r) {
                    // pair {y[P-4-2r], y[P-3-2r]}: even P from wA, odd P from wB
                    v2f pr = (P & 1) ? wB[slotBx(P - 3 - 2 * r)]
                                     : wA[slotA(P - 4 - 2 * r)];
                    if (r == 0)          A = cp[r] * pr;
                    else if (r == 1)     B = cp[r] * pr;
                    else if (r == 2)     C = cp[r] * pr;
                    else if (r % 3 == 0) A += cp[r] * pr;
                    else if (r % 3 == 1) B += cp[r] * pr;
                    else                 C += cp[r] * pr;
                }
                v2f S = (A + B) + C;
                float t1 = e + (S.x + S.y);
                float ym1 = (P & 1) ? wA[slotA(P - 1)].x  : wA[slotAy(P - 1)].y;  // y[P-1]
                float ym2 = (P & 1) ? wA[slotAy(P - 2)].y : wA[slotA(P - 2)].x;   // y[P-2]
                float u = fmaf(nc2, ym2, t1);
                float y = fmaf(nc1, ym1, u);

                // mirror write into both rings
                if (P & 1) {
                    wA[slotAy(P)].y = y;
                    wB[slotBx(P)].x = y;
                } else {
                    wA[slotA(P)].x = y;
                    wB[slotBy(P)].y = y;
                }
                k += dk;
            }

            if ((unsigned)(tg - s0) < 40u) {          // tg, s0 multiples of 8
                const int Q = 24 + gg * 8;            // Q even -> pairs from wA
                *(float4*)(orow + tg)     = make_float4(wA[slotA(Q + 0)].x, wA[slotA(Q + 0)].y,
                                                        wA[slotA(Q + 2)].x, wA[slotA(Q + 2)].y);
                *(float4*)(orow + tg + 4) = make_float4(wA[slotA(Q + 4)].x, wA[slotA(Q + 4)].y,
                                                        wA[slotA(Q + 6)].x, wA[slotA(Q + 6)].y);
            }
            if (gg < 9) {
                nc1 += dn1; nc2 += dn2;
#pragma unroll
                for (int r = 0; r < 11; ++r) cp[r] += d8[r];   // v_pk_add_f32
            }
            xc0 = xn0; xc1 = xn1;                     // rotate at group END
            xn0 = xf0; xn1 = xf1;
        }

        // Rotate coefficient buffers (register movs, ~50/frame).
        if (f < 2) {
#pragma unroll
            for (int q = 0; q < D_COEF; ++q) { ccur[q] = cnxt[q]; cnxt[q] = cfut[q]; }
        }
    }
}

extern "C" void kernel_launch(void* const* d_in, const int* in_sizes, int n_in,
                              void* d_out, int out_size, void* d_ws, size_t ws_size,
                              hipStream_t stream) {
    const float* x = (const float*)d_in[0];
    const float* a = (const float*)d_in[1];
    float* out = (float*)d_out;

    dim3 block(64);
    dim3 grid(BATCH * CHUNKS / 64);      // 800 one-wave blocks
    hipLaunchKernelGGL(lpc_kernel, grid, block, 0, stream, x, a, out);
}